// Round 12
// baseline (1228.646 us; speedup 1.0000x reference)
//
#include <hip/hip_runtime.h>
#include <hip/hip_bf16.h>

// Problem constants (from reference config)
#define CIN 256
#define COUT 256
#define HW 56
#define BATCH 8
#define L_SPATIAL 3136            // 56*56
#define K_TOTAL 2304              // CIN*3*3
#define NT 36                     // K chunks of 64
#define NH 18                     // n-chunks retained per wave (half)
#define ROWF (COUT * NT)          // 9216 floats per (b,l) row of psum
#define KSTRIDE 2312              // bf16 elems per m-row in LDS (+8 pad)
#define BUF_BYTES (16 * KSTRIDE * 2)     // 73,984 B: holds A-tile OR drain stage
#define CARRY_OFF (2 * BUF_BYTES)        // 147,968
#define LDS_BYTES (CARRY_OFF + 8192)     // 156,160 B <= 160 KiB -> 1 WG/CU, 16 waves
#define MT_TOTAL 1568             // m-tiles (8*3136/16)
#define TILES_PER_IMG 196
#define NWG 256                   // persistent: 1 WG per CU
#define QMAXF 127.0f
#define QMINF -128.0f

typedef short bf16x8 __attribute__((ext_vector_type(8)));
typedef float f32x4 __attribute__((ext_vector_type(4)));
typedef float f32x2 __attribute__((ext_vector_type(2)));

__device__ __forceinline__ void nt_store4(float* p, f32x4 v) {
  __builtin_nontemporal_store(v, reinterpret_cast<f32x4*>(p));
}

// LGKM-only barrier: orders LDS ops across the WG without draining outstanding
// global stores (vmcnt) -- the NT store stream stays in flight across phases.
__device__ __forceinline__ void lgkm_barrier() {
  __builtin_amdgcn_sched_barrier(0);
  asm volatile("s_waitcnt lgkmcnt(0)" ::: "memory");
  __builtin_amdgcn_s_barrier();
  asm volatile("" ::: "memory");
  __builtin_amdgcn_sched_barrier(0);
}

// ---- prep: Bsign[c][k] = sign(w) as bf16 (B^T layout = MFMA B-frag order), scale[c] = mean|w| ----
__global__ __launch_bounds__(256) void prep_kernel(
    const float* __restrict__ w, unsigned short* __restrict__ bsign,
    float* __restrict__ scale) {
  const int c = blockIdx.x;
  const int t = threadIdx.x;
  const float* row = w + (size_t)c * K_TOTAL;
  unsigned short* out = bsign + (size_t)c * K_TOTAL;
  float acc = 0.0f;
#pragma unroll
  for (int j = 0; j < 9; ++j) {
    const int k = t + 256 * j;
    const float v = row[k];
    acc += __builtin_fabsf(v);
    out[k] = (v > 0.0f) ? (unsigned short)0x3F80
           : ((v < 0.0f) ? (unsigned short)0xBF80 : (unsigned short)0);
  }
#pragma unroll
  for (int o = 32; o > 0; o >>= 1) acc += __shfl_down(acc, o, 64);
  __shared__ float red[4];
  if ((t & 63) == 0) red[t >> 6] = acc;
  __syncthreads();
  if (t == 0) scale[c] = (red[0] + red[1] + red[2] + red[3]) * (1.0f / 2304.0f);
}

// Build one 16-row A tile (bf16 im2col) into the given LDS buffer.
__device__ __forceinline__ void build_atile(
    const float* __restrict__ xb, unsigned short* __restrict__ Atile,
    int tid, int l0) {
  const int ml = tid & 15;
  const int grp = tid >> 4;                   // 0..63
  const int l = l0 + ml;                      // never crosses image (l0 mult of 16)
  const int oh = l / HW;
  const int ow = l - oh * HW;
  unsigned short* arow = Atile + ml * KSTRIDE;
  for (int r = grp; r < 768; r += 64) {       // r = ci*3 + kh; 12 iters
    const int ci = r / 3;
    const int kh = r - ci * 3;
    const int hh = oh + kh - 1;
    const bool hv = ((unsigned)hh < (unsigned)HW);
    const float* xr = xb + (ci * HW + hh) * HW;
    const int kb = ci * 9 + kh * 3;
#pragma unroll
    for (int kw = 0; kw < 3; ++kw) {
      const int wv = ow + kw - 1;
      float v = 0.0f;
      if (hv && ((unsigned)wv < (unsigned)HW)) v = xr[wv];
      __hip_bfloat16 bv = __float2bfloat16(v);
      arow[kb + kw] = *reinterpret_cast<unsigned short*>(&bv);
    }
  }
}

// Compute 18 chunks [H*18, H*18+18), retain all in ps[]; H==0 also runs the
// saturating scan prefix (carry starts UNCLIPPED at chunk 0, matching ref).
// Depth-2 rotating B prefetch (3 slots, all indices compile-time via unroll).
template <int H>
__device__ __forceinline__ void compute18(
    const unsigned short* __restrict__ aptr,
    const unsigned short* __restrict__ bptr,
    f32x4* __restrict__ ps, f32x4& sacc) {
  const f32x4 zero = {0.0f, 0.0f, 0.0f, 0.0f};
  const unsigned short* ap = aptr + H * NH * 64;
  const unsigned short* bp = bptr + H * NH * 64;
  bf16x8 b0[3], b1[3];
  b0[0] = *reinterpret_cast<const bf16x8*>(bp);
  b1[0] = *reinterpret_cast<const bf16x8*>(bp + 32);
  b0[1] = *reinterpret_cast<const bf16x8*>(bp + 64);
  b1[1] = *reinterpret_cast<const bf16x8*>(bp + 96);
#pragma unroll
  for (int j = 0; j < NH; ++j) {
    if (j + 2 < NH) {                     // prefetch 2 iterations ahead
      b0[(j + 2) % 3] = *reinterpret_cast<const bf16x8*>(bp + (j + 2) * 64);
      b1[(j + 2) % 3] = *reinterpret_cast<const bf16x8*>(bp + (j + 2) * 64 + 32);
    }
    bf16x8 a0 = *reinterpret_cast<const bf16x8*>(ap + j * 64);
    bf16x8 a1 = *reinterpret_cast<const bf16x8*>(ap + j * 64 + 32);
    f32x4 acc = __builtin_amdgcn_mfma_f32_16x16x32_bf16(a0, b0[j % 3], zero, 0, 0, 0);
    acc = __builtin_amdgcn_mfma_f32_16x16x32_bf16(a1, b1[j % 3], acc, 0, 0, 0);
    ps[j] = acc;
    if (H == 0) {
      if (j == 0) {
        sacc = acc;
      } else {
#pragma unroll
        for (int e = 0; e < 4; ++e)
          sacc[e] = __builtin_amdgcn_fmed3f(sacc[e] + acc[e], QMINF, QMAXF);
      }
    }
  }
}

// ---- main: PERSISTENT WGs (256, one/CU), each looping its 6-7 m-tiles of one
// image (t = w + 256k -> t%8 = w%8 fixed -> XCD-image affinity + warm L2 x).
// Two 74KB LDS buffers swap roles per tile: A(t) in buf[p], stage(t) in buf[p^1];
// after the last drain read, A(t+1) is built into buf[p^1] while tile t's NT
// stores drain in the background (lgkm barriers keep them in flight). This
// pipelines drain(t) || build(t+1) || compute(t+1) -- the cross-phase overlap
// every previous (WG-per-tile) variant structurally lacked.
__global__ __launch_bounds__(1024, 4) void satconv_kernel(
    const float* __restrict__ x, const unsigned short* __restrict__ bsign,
    const float* __restrict__ scale, float* __restrict__ y_out,
    float* __restrict__ psum_out) {
  extern __shared__ char smem[];
  float* carryb = (float*)(smem + CARRY_OFF);           // [8][256] f32

  const int tid = threadIdx.x;
  const int w = blockIdx.x;
  const int b_img = w & 7;                    // fixed image per WG
  const float* xb = x + (size_t)b_img * (CIN * L_SPATIAL);

  const int lane = tid & 63;
  const int cl = lane & 15;
  const int q = lane >> 4;
  const int wave = tid >> 6;                  // 0..15
  const int cs = wave >> 1;                   // 0..7: c-subtile pair id
  const int h = wave & 1;                     // n-half

  const float sc_s0 = scale[cs * 16 + cl];    // c fixed per WG across all tiles
  const float sc_s1 = scale[128 + cs * 16 + cl];

  // m0-independent part of the drain store indices (R0 decode: f -> (qq,ci,n0))
  int rel_it[9];
  {
#pragma unroll
    for (int it = 0; it < 9; ++it) {
      const int f = it * 256 + lane * 4;
      const int qq = f / 576;
      const int rem = f - qq * 576;
      const int ci = rem / 36;
      const int n0 = rem - ci * 36;
      rel_it[it] = ((qq << 2) * COUT + ci) * NT + n0;
    }
  }

  int p = 0;
  int t = w;
  build_atile(xb, (unsigned short*)smem, tid, (t >> 3) << 4);
  __syncthreads();                            // first tile: nothing in flight yet

  while (t < MT_TOTAL) {
    const int l0 = (t >> 3) << 4;
    const int m0 = (b_img * TILES_PER_IMG + (t >> 3)) << 4;
    const int mbase = m0 * ROWF;              // < 2^31, fits int
    unsigned short* Atile = (unsigned short*)(smem + p * BUF_BYTES);
    float* stage = (float*)(smem + (p ^ 1) * BUF_BYTES);
    float* reg = stage + cs * 2304;           // per-pair staging region
    const unsigned short* aptr = Atile + cl * KSTRIDE + q * 8;

    for (int s = 0; s < 2; ++s) {
      const int csub0 = (s << 7) + (cs << 4); // c-subtile base (0..240)
      const int c = csub0 + cl;
      const unsigned short* bptr = bsign + (size_t)c * K_TOTAL + q * 8;

      f32x4 ps[NH];
      f32x4 sacc = {0.0f, 0.0f, 0.0f, 0.0f};
      if (h == 0) compute18<0>(aptr, bptr, ps, sacc);
      else        compute18<1>(aptr, bptr, ps, sacc);

      // ---- carry hand-off: h0 -> h1 (per (cs, cl, q), f32x4 over the 4 m's) ----
      if (h == 0)
        *reinterpret_cast<f32x4*>(carryb + cs * 256 + lane * 4) = sacc;
      lgkm_barrier();                         // LDS-order only; stores stay in flight
      if (h == 1) {
        f32x4 cin = *reinterpret_cast<const f32x4*>(carryb + cs * 256 + lane * 4);
#pragma unroll
        for (int j = 0; j < NH; ++j) {
#pragma unroll
          for (int e = 0; e < 4; ++e)
            cin[e] = __builtin_amdgcn_fmed3f(cin[e] + ps[j][e], QMINF, QMAXF);
        }
        const float sc = (s == 0) ? sc_s0 : sc_s1;
        f32x4 yv;
#pragma unroll
        for (int e = 0; e < 4; ++e) yv[e] = cin[e] * sc;
        nt_store4(y_out + ((size_t)b_img * COUT + c) * L_SPATIAL + l0 + (q << 2), yv);
      }

      // ---- psum drain: 4 rg rounds; pair stages [q][16c][36n] (2304 f32), then
      // both waves copy out dense 1KB full-line NT stores (h0: it 0-4, h1: 5-8).
      const int soff = csub0 * NT;
#pragma unroll
      for (int rg = 0; rg < 4; ++rg) {
        {
          // writer: 18 floats at reg[q*576 + cl*36 + h*18], vectorized b128/b64
          float* wr = reg + q * 576 + cl * 36 + h * NH;
          if (h == 0) {
            f32x4 v;
#pragma unroll
            for (int g = 0; g < 4; ++g) {
              v[0] = ps[4 * g + 0][rg]; v[1] = ps[4 * g + 1][rg];
              v[2] = ps[4 * g + 2][rg]; v[3] = ps[4 * g + 3][rg];
              *reinterpret_cast<f32x4*>(wr + 4 * g) = v;
            }
            f32x2 tl = {ps[16][rg], ps[17][rg]};
            *reinterpret_cast<f32x2*>(wr + 16) = tl;
          } else {
            f32x2 tl = {ps[0][rg], ps[1][rg]};
            *reinterpret_cast<f32x2*>(wr) = tl;
            f32x4 v;
#pragma unroll
            for (int g = 0; g < 4; ++g) {
              v[0] = ps[4 * g + 2][rg]; v[1] = ps[4 * g + 3][rg];
              v[2] = ps[4 * g + 4][rg]; v[3] = ps[4 * g + 5][rg];
              *reinterpret_cast<f32x4*>(wr + 2 + 4 * g) = v;
            }
          }
        }
        lgkm_barrier();                       // stage visible; no vmcnt drain
        {
          const int rgoff = rg * ROWF + soff;
          const int it0 = (h == 0) ? 0 : 5;
          const int it1 = (h == 0) ? 5 : 9;
          for (int it = it0; it < it1; ++it) {
            f32x4 v = *reinterpret_cast<const f32x4*>(reg + it * 256 + lane * 4);
            nt_store4(psum_out + (size_t)(mbase + rel_it[it] + rgoff), v);
          }
        }
        lgkm_barrier();                       // drain ds_reads done -> stage reusable
      }
    }

    // ---- cross-tile pipeline: build A(t+1) into the stage buffer (drain reads
    // completed at the last lgkm_barrier) while this tile's NT stores drain.
    const int tn = t + NWG;
    if (tn < MT_TOTAL)
      build_atile(xb, (unsigned short*)(smem + (p ^ 1) * BUF_BYTES), tid,
                  (tn >> 3) << 4);
    lgkm_barrier();                           // A(t+1) visible; stores in flight
    p ^= 1;
    t = tn;
  }
}

extern "C" void kernel_launch(void* const* d_in, const int* in_sizes, int n_in,
                              void* d_out, int out_size, void* d_ws, size_t ws_size,
                              hipStream_t stream) {
  const float* x = (const float*)d_in[0];
  const float* w = (const float*)d_in[1];
  float* y = (float*)d_out;
  float* psum = y + (size_t)BATCH * COUT * L_SPATIAL;            // y is 6,422,528 floats
  unsigned short* bsign = (unsigned short*)d_ws;                 // 256*2304*2 = 1,179,648 B
  float* scale = (float*)((char*)d_ws + (size_t)COUT * K_TOTAL * 2);

  prep_kernel<<<COUT, 256, 0, stream>>>(w, bsign, scale);

  hipFuncSetAttribute(reinterpret_cast<const void*>(satconv_kernel),
                      hipFuncAttributeMaxDynamicSharedMemorySize, LDS_BYTES);
  satconv_kernel<<<NWG, 1024, LDS_BYTES, stream>>>(
      x, bsign, scale, y, psum);
}

// Round 17
// 1167.455 us; speedup vs baseline: 1.0524x; 1.0524x over previous
//
#include <hip/hip_runtime.h>
#include <hip/hip_bf16.h>

// Problem constants
#define CIN 256
#define COUT 256
#define HW 56
#define BATCH 8
#define L_SPATIAL 3136            // 56*56
#define K_TOTAL 2304              // CIN*3*3
#define NT 36                     // K chunks of 64
#define NTH 12                    // chunks per n-third (3 thirds)
#define ROWF (COUT * NT)          // 9216 floats per (b,l) row of psum
#define KSTRIDE 2312              // bf16 elems per m-row in LDS (+8 pad)
#define ATILE_BYTES (16 * KSTRIDE * 2)   // 73,984
#define SLOT0_OFF ATILE_BYTES            // two 36,864B rg-round slots
#define SLOT1_OFF (ATILE_BYTES + 36864)
#define CARRY_OFF (ATILE_BYTES + 73728)  // 4 KB carry: [cg4][cl16][q4] f32x4
#define YSTAGE_OFF (CARRY_OFF + 4096)    // 4 KB ystage: [cg4][cl16][q4] f32x4
#define LDS_BYTES (YSTAGE_OFF + 4096)    // 155,904 <= 160 KiB
#define MT_TOTAL 1568
#define TILES_PER_IMG 196
#define NWG 256                   // persistent: 1 WG per CU
#define QMAXF 127.0f
#define QMINF -128.0f

typedef short bf16x8 __attribute__((ext_vector_type(8)));
typedef float f32x4 __attribute__((ext_vector_type(4)));

__device__ __forceinline__ void nt_store4(float* p, f32x4 v) {
  __builtin_nontemporal_store(v, reinterpret_cast<f32x4*>(p));
}

// LGKM-only barrier: orders LDS ops WG-wide without touching vmcnt.
__device__ __forceinline__ void lgkm_barrier() {
  __builtin_amdgcn_sched_barrier(0);
  asm volatile("s_waitcnt lgkmcnt(0)" ::: "memory");
  __builtin_amdgcn_s_barrier();
  asm volatile("" ::: "memory");
  __builtin_amdgcn_sched_barrier(0);
}

// ---- prep: Bsign[c][k] = sign(w) as bf16 (B-frag order), scale[c] = mean|w| ----
__global__ __launch_bounds__(256) void prep_kernel(
    const float* __restrict__ w, unsigned short* __restrict__ bsign,
    float* __restrict__ scale) {
  const int c = blockIdx.x;
  const int t = threadIdx.x;
  const float* row = w + (size_t)c * K_TOTAL;
  unsigned short* out = bsign + (size_t)c * K_TOTAL;
  float acc = 0.0f;
#pragma unroll
  for (int j = 0; j < 9; ++j) {
    const int k = t + 256 * j;
    const float v = row[k];
    acc += __builtin_fabsf(v);
    out[k] = (v > 0.0f) ? (unsigned short)0x3F80
           : ((v < 0.0f) ? (unsigned short)0xBF80 : (unsigned short)0);
  }
#pragma unroll
  for (int o = 32; o > 0; o >>= 1) acc += __shfl_down(acc, o, 64);
  __shared__ float red[4];
  if ((t & 63) == 0) red[t >> 6] = acc;
  __syncthreads();
  if (t == 0) scale[c] = (red[0] + red[1] + red[2] + red[3]) * (1.0f / 2304.0f);
}

// Build one 16-row A tile (bf16 im2col). grpN = number of 16-thread groups.
__device__ __forceinline__ void build_atile(
    const float* __restrict__ xb, unsigned short* __restrict__ Atile,
    int tid, int grpN, int l0) {
  const int ml = tid & 15;
  const int grp = tid >> 4;
  const int l = l0 + ml;
  const int oh = l / HW;
  const int ow = l - oh * HW;
  unsigned short* arow = Atile + ml * KSTRIDE;
  for (int r = grp; r < 768; r += grpN) {     // r = ci*3 + kh
    const int ci = r / 3;
    const int kh = r - ci * 3;
    const int hh = oh + kh - 1;
    const bool hv = ((unsigned)hh < (unsigned)HW);
    const float* xr = xb + (ci * HW + hh) * HW;
    const int kb = ci * 9 + kh * 3;
#pragma unroll
    for (int kw = 0; kw < 3; ++kw) {
      const int wv = ow + kw - 1;
      float v = 0.0f;
      if (hv && ((unsigned)wv < (unsigned)HW)) v = xr[wv];
      __hip_bfloat16 bv = __float2bfloat16(v);
      arow[kb + kw] = *reinterpret_cast<unsigned short*>(&bv);
    }
  }
}

// Compute 12 chunks [H*12, H*12+12), retain in ps[]; H==0 runs the scan prefix.
template <int H>
__device__ __forceinline__ void compute12(
    const unsigned short* __restrict__ aptr,
    const unsigned short* __restrict__ bptr,
    f32x4* __restrict__ ps, f32x4& sacc) {
  const f32x4 zero = {0.0f, 0.0f, 0.0f, 0.0f};
  const unsigned short* ap = aptr + H * NTH * 64;
  const unsigned short* bp = bptr + H * NTH * 64;
  bf16x8 b0[3], b1[3];
  b0[0] = *reinterpret_cast<const bf16x8*>(bp);
  b1[0] = *reinterpret_cast<const bf16x8*>(bp + 32);
  b0[1] = *reinterpret_cast<const bf16x8*>(bp + 64);
  b1[1] = *reinterpret_cast<const bf16x8*>(bp + 96);
#pragma unroll
  for (int j = 0; j < NTH; ++j) {
    if (j + 2 < NTH) {
      b0[(j + 2) % 3] = *reinterpret_cast<const bf16x8*>(bp + (j + 2) * 64);
      b1[(j + 2) % 3] = *reinterpret_cast<const bf16x8*>(bp + (j + 2) * 64 + 32);
    }
    bf16x8 a0 = *reinterpret_cast<const bf16x8*>(ap + j * 64);
    bf16x8 a1 = *reinterpret_cast<const bf16x8*>(ap + j * 64 + 32);
    f32x4 acc = __builtin_amdgcn_mfma_f32_16x16x32_bf16(a0, b0[j % 3], zero, 0, 0, 0);
    acc = __builtin_amdgcn_mfma_f32_16x16x32_bf16(a1, b1[j % 3], acc, 0, 0, 0);
    ps[j] = acc;
    if (H == 0) {
      if (j == 0) {
        sacc = acc;                 // scan carry starts UNCLIPPED (matches ref)
      } else {
#pragma unroll
        for (int e = 0; e < 4; ++e)
          sacc[e] = __builtin_amdgcn_fmed3f(sacc[e] + acc[e], QMINF, QMAXF);
      }
    }
  }
}

// Producer dump of one rg-round slice (compile-time RG keeps ps indices static).
template <int RG>
__device__ __forceinline__ void dump_rg(float* slot, int cg, int h, int cl, int q,
                                        const f32x4* __restrict__ ps) {
  float* wr = slot + cg * 2304 + q * 576 + cl * 36 + h * NTH;
#pragma unroll
  for (int g = 0; g < 3; ++g) {
    f32x4 v = {ps[4 * g + 0][RG], ps[4 * g + 1][RG],
               ps[4 * g + 2][RG], ps[4 * g + 3][RG]};
    *reinterpret_cast<f32x4*>(wr + 4 * g) = v;
  }
}

// Consumer: 9 full-sector 1KB NT stores of one staged rg-round.
__device__ __forceinline__ void drain_rg(
    const char* smem, int slotOff, float* __restrict__ psum_out,
    int addrBase, const int* __restrict__ rel_it, int ci, int lane) {
  const float* sl = (const float*)(smem + slotOff);
#pragma unroll
  for (int it = 0; it < 9; ++it) {
    f32x4 v = *reinterpret_cast<const f32x4*>(sl + (ci * 9 + it) * 256 + lane * 4);
    nt_store4(psum_out + (size_t)(addrBase + rel_it[it]), v);
  }
}

// ---- main: PERSISTENT WGs, 16 waves = 12 PRODUCERS (4 c-groups x 3 n-thirds,
// ps[12]) + 4 STORE waves. vmcnt is per-wave FIFO shared by loads+stores: in all
// prior variants every wave's next-pass B-load consumption waited for its own
// store burst to retire at HBM. Producers here issue ONLY loads (x, bsign);
// consumers issue ONLY stores (from LDS stage) -- decoupled queues. Slots are
// double-buffered 36KB rg-rounds; all barriers lgkm-only; scan stitched h0->h1->h2
// via LDS carry (order identical to ref: chunks 0..35 sequential, first unclipped).
__global__ __launch_bounds__(1024, 4) void satconv_kernel(
    const float* __restrict__ x, const unsigned short* __restrict__ bsign,
    const float* __restrict__ scale, float* __restrict__ y_out,
    float* __restrict__ psum_out) {
  extern __shared__ char smem[];
  unsigned short* Atile = (unsigned short*)smem;

  const int tid = threadIdx.x;
  const int w = blockIdx.x;
  const int b_img = w & 7;                    // image == XCD (round-robin dispatch)
  const float* xb = x + (size_t)b_img * (CIN * L_SPATIAL);

  const int lane = tid & 63;
  const int wave = tid >> 6;                  // 0..15
  const int cl = lane & 15;
  const int q = lane >> 4;
  const bool is_prod = (wave < 12);
  const int cg = wave & 3;                    // producer c-group (32 c)
  const int h = wave >> 2;                    // producer n-third 0..2 (waves 0..11)
  const int ci = is_prod ? 0 : (wave - 12);   // consumer id 0..3

  // producer h2: prefetch the 4 per-(s,tt) scales (c fixed across tiles)
  float scv[4];
#pragma unroll
  for (int st = 0; st < 4; ++st)
    scv[st] = scale[(st >> 1) * 128 + cg * 32 + (st & 1) * 16 + cl];

  // consumer: precompute store-decode (tile-invariant)
  int rel_it[9];
#pragma unroll
  for (int it = 0; it < 9; ++it) {
    const int f = (ci * 9 + it) * 256 + lane * 4;
    const int cg_d = f / 2304;
    const int r1 = f - cg_d * 2304;
    const int q_d = r1 / 576;
    const int r2 = r1 - q_d * 576;
    const int cl_d = r2 / 36;
    const int n0 = r2 - cl_d * 36;
    rel_it[it] = (q_d * 4) * ROWF + (cg_d * 32 + cl_d) * 36 + n0;
  }

  // first A tile: all 16 waves build
  build_atile(xb, Atile, tid, 64, ((w) >> 3) << 4);
  __syncthreads();

  const unsigned short* aptr = Atile + cl * KSTRIDE + q * 8;
  float* const slot0 = (float*)(smem + SLOT0_OFF);
  float* const slot1 = (float*)(smem + SLOT1_OFF);
  float* const carryb = (float*)(smem + CARRY_OFF);
  float* const ystage = (float*)(smem + YSTAGE_OFF);

  int pend = 0;
  int pend_base2 = 0, pend_base3 = 0, pend_s = 0, pend_tt = 0, pend_l0 = 0;

  for (int t = w; t < MT_TOTAL; t += NWG) {
    const int tileIdx = t >> 3;
    const int l0 = tileIdx << 4;
    const int m0 = (b_img * TILES_PER_IMG + tileIdx) << 4;
    const int m0row = m0 * ROWF;              // < 2^31

#pragma unroll 1
    for (int st = 0; st < 4; ++st) {
      const int s = st >> 1, tt = st & 1;
      const int soff = (s * 128 + tt * 16) * NT;

      f32x4 ps[NTH];
      f32x4 sacc = {0.0f, 0.0f, 0.0f, 0.0f};

      // ---- P0: producers compute; consumers drain pending rg2/rg3 + y ----
      if (is_prod) {
        const int c = s * 128 + cg * 32 + tt * 16 + cl;
        const unsigned short* bptr = bsign + (size_t)c * K_TOTAL + q * 8;
        if (h == 0)      compute12<0>(aptr, bptr, ps, sacc);
        else if (h == 1) compute12<1>(aptr, bptr, ps, sacc);
        else             compute12<2>(aptr, bptr, ps, sacc);
        if (h == 0)
          *reinterpret_cast<f32x4*>(carryb + cg * 256 + cl * 16 + q * 4) = sacc;
      } else if (pend) {
        drain_rg(smem, SLOT0_OFF, psum_out, pend_base2, rel_it, ci, lane);
        drain_rg(smem, SLOT1_OFF, psum_out, pend_base3, rel_it, ci, lane);
        f32x4 v = *reinterpret_cast<const f32x4*>(ystage + ci * 256 + lane * 4);
        const int c = pend_s * 128 + ci * 32 + pend_tt * 16 + (lane >> 2);
        nt_store4(y_out + ((size_t)b_img * COUT + c) * L_SPATIAL + pend_l0 +
                      ((lane & 3) << 2), v);
      }
      lgkm_barrier();

      // ---- P1: producers dump rg0/rg1; h1 stitches carry ----
      if (is_prod) {
        dump_rg<0>(slot0, cg, h, cl, q, ps);
        dump_rg<1>(slot1, cg, h, cl, q, ps);
        if (h == 1) {
          f32x4 cin = *reinterpret_cast<const f32x4*>(carryb + cg * 256 + cl * 16 + q * 4);
#pragma unroll
          for (int j = 0; j < NTH; ++j)
#pragma unroll
            for (int e = 0; e < 4; ++e)
              cin[e] = __builtin_amdgcn_fmed3f(cin[e] + ps[j][e], QMINF, QMAXF);
          *reinterpret_cast<f32x4*>(carryb + cg * 256 + cl * 16 + q * 4) = cin;
        }
      }
      lgkm_barrier();

      // ---- P2: h2 finishes scan -> ystage; consumers drain rg0/rg1 ----
      if (is_prod) {
        if (h == 2) {
          f32x4 cin = *reinterpret_cast<const f32x4*>(carryb + cg * 256 + cl * 16 + q * 4);
#pragma unroll
          for (int j = 0; j < NTH; ++j)
#pragma unroll
            for (int e = 0; e < 4; ++e)
              cin[e] = __builtin_amdgcn_fmed3f(cin[e] + ps[j][e], QMINF, QMAXF);
          const float sc = scv[st];
          f32x4 yv;
#pragma unroll
          for (int e = 0; e < 4; ++e) yv[e] = cin[e] * sc;
          *reinterpret_cast<f32x4*>(ystage + cg * 256 + cl * 16 + q * 4) = yv;
        }
      } else {
        drain_rg(smem, SLOT0_OFF, psum_out, m0row + 0 * ROWF + soff, rel_it, ci, lane);
        drain_rg(smem, SLOT1_OFF, psum_out, m0row + 1 * ROWF + soff, rel_it, ci, lane);
      }
      lgkm_barrier();

      // ---- P3: producers dump rg2/rg3 ----
      if (is_prod) {
        dump_rg<2>(slot0, cg, h, cl, q, ps);
        dump_rg<3>(slot1, cg, h, cl, q, ps);
      }
      lgkm_barrier();

      pend = 1;
      pend_base2 = m0row + 2 * ROWF + soff;
      pend_base3 = m0row + 3 * ROWF + soff;
      pend_s = s; pend_tt = tt; pend_l0 = l0;
    }

    // ---- tile end: producers build A(t+NWG); consumers drain pending ----
    const int tn = t + NWG;
    if (is_prod) {
      if (tn < MT_TOTAL) build_atile(xb, Atile, tid, 48, (tn >> 3) << 4);
    } else if (pend) {
      drain_rg(smem, SLOT0_OFF, psum_out, pend_base2, rel_it, ci, lane);
      drain_rg(smem, SLOT1_OFF, psum_out, pend_base3, rel_it, ci, lane);
      f32x4 v = *reinterpret_cast<const f32x4*>(ystage + ci * 256 + lane * 4);
      const int c = pend_s * 128 + ci * 32 + pend_tt * 16 + (lane >> 2);
      nt_store4(y_out + ((size_t)b_img * COUT + c) * L_SPATIAL + pend_l0 +
                    ((lane & 3) << 2), v);
    }
    pend = 0;
    lgkm_barrier();
  }
}

extern "C" void kernel_launch(void* const* d_in, const int* in_sizes, int n_in,
                              void* d_out, int out_size, void* d_ws, size_t ws_size,
                              hipStream_t stream) {
  const float* x = (const float*)d_in[0];
  const float* w = (const float*)d_in[1];
  float* y = (float*)d_out;
  float* psum = y + (size_t)BATCH * COUT * L_SPATIAL;
  unsigned short* bsign = (unsigned short*)d_ws;                 // 1,179,648 B
  float* scale = (float*)((char*)d_ws + (size_t)COUT * K_TOTAL * 2);

  prep_kernel<<<COUT, 256, 0, stream>>>(w, bsign, scale);

  hipFuncSetAttribute(reinterpret_cast<const void*>(satconv_kernel),
                      hipFuncAttributeMaxDynamicSharedMemorySize, LDS_BYTES);
  satconv_kernel<<<NWG, 1024, LDS_BYTES, stream>>>(
      x, bsign, scale, y, psum);
}